// Round 5
// baseline (589.660 us; speedup 1.0000x reference)
//
#include <hip/hip_runtime.h>

#define BB 4
#define CC 256
#define DD 32
#define SS 4096

typedef __bf16 bf16;
typedef __bf16 bf16x8 __attribute__((ext_vector_type(8)));
typedef __bf16 bf16x4 __attribute__((ext_vector_type(4)));
typedef float f32x4 __attribute__((ext_vector_type(4)));
typedef unsigned int u32;
typedef u32 u32x4 __attribute__((ext_vector_type(4)));
typedef unsigned short u16;

// workspace layout (bf16 elements):
//  q:  [2][BB][SS][DD]  off 0         (pos-major, 32 d inner)
//  k:  [2][BB][SS][DD]  off 1048576
//  v:  [2][BB][CC][SS]  off 2097152   (c-major, pos inner)
//  wb: [320][CC]        off 10485760  (bf16 Wq|Wk|Wv stacked)
#define Q_OFF  0
#define K_OFF  1048576
#define V_OFF  2097152
#define WB_OFF 10485760

static __device__ __forceinline__ u32 pack2(float lo, float hi) {
    bf16 a = (bf16)lo, b = (bf16)hi;
    u16 ua = __builtin_bit_cast(u16, a), ub = __builtin_bit_cast(u16, b);
    return (u32)ua | ((u32)ub << 16);
}

// LDS-only barrier: drain ds ops, sync, but let global loads stay in flight
// (__syncthreads emits s_waitcnt vmcnt(0) which defeats register prefetch).
static __device__ __forceinline__ void bar_lds() {
    asm volatile("s_waitcnt lgkmcnt(0)" ::: "memory");
    __builtin_amdgcn_s_barrier();
    asm volatile("" ::: "memory");
}

// ------------------------------------------------- W fp32 -> bf16 [320][256]
__global__ __launch_bounds__(256) void convert_w_kernel(
    const float* __restrict__ Wq, const float* __restrict__ Wk,
    const float* __restrict__ Wv, bf16* __restrict__ wb)
{
    const int gid = blockIdx.x*256 + threadIdx.x;    // 40 blocks -> 10240
    const int idx = gid*8;
    const int o = idx >> 8, cc = idx & 255;
    const float* row = (o < 32) ? (Wq + (size_t)o*CC)
                     : (o < 64) ? (Wk + (size_t)(o-32)*CC)
                                : (Wv + (size_t)(o-64)*CC);
    const float4 a = *(const float4*)(row + cc);
    const float4 c = *(const float4*)(row + cc + 4);
    bf16x8 pk;
    pk[0]=(bf16)a.x; pk[1]=(bf16)a.y; pk[2]=(bf16)a.z; pk[3]=(bf16)a.w;
    pk[4]=(bf16)c.x; pk[5]=(bf16)c.y; pk[6]=(bf16)c.z; pk[7]=(bf16)c.w;
    *(bf16x8*)(wb + idx) = pk;
}

// ------------------------------------------------- fused q,k,v projection (MFMA)
// C[pos][o] = sum_cc X[cc][pos]*W[o][cc] + bias;  o: 0-31 q, 32-63 k, 64-319 v
// Double-buffered xT + register X-prefetch; bar_lds (no vmcnt drain) keeps the
// global prefetches in flight across the per-chunk barrier.
__global__ __launch_bounds__(256, 2) void proj_all_kernel(
    const float* __restrict__ x, const float* __restrict__ y,
    const bf16* __restrict__ wb,
    const float* __restrict__ bq, const float* __restrict__ bk,
    const float* __restrict__ bv,
    bf16* __restrict__ qout, bf16* __restrict__ kout, bf16* __restrict__ vout)
{
    // xT: [2][64 pos][40 bf16] (row 80 B, 16B-aligned)
    __shared__ __align__(16) char smem[2*5120];
    bf16* xT  = (bf16*)smem;
    u32*  xTw = (u32*)smem;

    const int t    = threadIdx.x;
    const int lane = t & 63;
    const int w    = t >> 6;
    const int ln   = lane & 15;
    const int quad = lane >> 4;

    const int bid  = blockIdx.x;
    const int dirb = bid & 7;
    const int src  = dirb >> 2;
    const int b    = dirb & 3;
    const int i0   = (bid >> 3) * 64;
    const float* in = src ? y : x;
    const float* xbase = in + (size_t)b*CC*SS + i0;

    const int cp = t >> 4;            // cc-pair 0..15 -> cc {2cp, 2cp+1}
    const int pq = (t & 15) * 4;      // pos 0..60

    float bias[5];
    #pragma unroll
    for (int nbl = 0; nbl < 5; ++nbl) {
        const int o = 80*w + nbl*16 + ln;
        bias[nbl] = (o < 32) ? bq[o] : (o < 64) ? bk[o-32] : bv[o-64];
    }
    f32x4 acc[4][5];
    #pragma unroll
    for (int mb = 0; mb < 4; ++mb)
        #pragma unroll
        for (int nbl = 0; nbl < 5; ++nbl)
            acc[mb][nbl] = (f32x4){bias[nbl], bias[nbl], bias[nbl], bias[nbl]};

    const bf16* wrow = wb + (size_t)(80*w + ln)*CC + quad*8;
    bf16x8 bf[5];
    #pragma unroll
    for (int nbl = 0; nbl < 5; ++nbl)
        bf[nbl] = *(const bf16x8*)(wrow + (size_t)nbl*16*CC);

    // stage chunk 0 into buf0
    {
        const float* r0 = xbase + (size_t)(2*cp)*SS + pq;
        const float4 a0 = *(const float4*)r0;
        const float4 a1 = *(const float4*)(r0 + SS);
        xTw[(pq+0)*20 + cp] = pack2(a0.x, a1.x);
        xTw[(pq+1)*20 + cp] = pack2(a0.y, a1.y);
        xTw[(pq+2)*20 + cp] = pack2(a0.z, a1.z);
        xTw[(pq+3)*20 + cp] = pack2(a0.w, a1.w);
    }
    // prefetch chunk 1 into regs
    float4 a0, a1;
    {
        const float* r1 = xbase + (size_t)(32 + 2*cp)*SS + pq;
        a0 = *(const float4*)r1;
        a1 = *(const float4*)(r1 + SS);
    }
    bar_lds();

    for (int n = 0; n < 8; ++n) {
        bf16x8 af[4];
        #pragma unroll
        for (int mb = 0; mb < 4; ++mb)
            af[mb] = *(const bf16x8*)(xT + (n&1)*2560 + (mb*16 + ln)*40 + quad*8);
        // write prefetched chunk n+1 into other buffer
        if (n < 7) {
            u32* dst = xTw + ((n+1)&1)*1280;
            dst[(pq+0)*20 + cp] = pack2(a0.x, a1.x);
            dst[(pq+1)*20 + cp] = pack2(a0.y, a1.y);
            dst[(pq+2)*20 + cp] = pack2(a0.z, a1.z);
            dst[(pq+3)*20 + cp] = pack2(a0.w, a1.w);
        }
        // prefetch chunk n+2 regs (wrap keeps loads in-bounds; redundant at tail)
        {
            const int cc2 = ((n+2)*32) & 255;
            const float* r2 = xbase + (size_t)(cc2 + 2*cp)*SS + pq;
            a0 = *(const float4*)r2;
            a1 = *(const float4*)(r2 + SS);
        }
        #pragma unroll
        for (int mb = 0; mb < 4; ++mb)
            #pragma unroll
            for (int nbl = 0; nbl < 5; ++nbl)
                acc[mb][nbl] = __builtin_amdgcn_mfma_f32_16x16x32_bf16(
                                   af[mb], bf[nbl], acc[mb][nbl], 0, 0, 0);
        // prefetch next W chunk
        const int ccn = ((n+1)*32) & 255;
        #pragma unroll
        for (int nbl = 0; nbl < 5; ++nbl)
            bf[nbl] = *(const bf16x8*)(wrow + (size_t)nbl*16*CC + ccn);
        bar_lds();
    }

    bf16* qo = qout + (size_t)(src*BB + b)*SS*DD;
    bf16* ko = kout + (size_t)(src*BB + b)*SS*DD;
    bf16* vo = vout + (size_t)(src*BB + b)*CC*SS;
    #pragma unroll
    for (int nbl = 0; nbl < 5; ++nbl) {
        const int o = 80*w + nbl*16 + ln;
        if (o < 32) {
            #pragma unroll
            for (int mb = 0; mb < 4; ++mb)
                #pragma unroll
                for (int r = 0; r < 4; ++r)
                    qo[(size_t)(i0 + mb*16 + quad*4 + r)*DD + o] = (bf16)acc[mb][nbl][r];
        } else if (o < 64) {
            #pragma unroll
            for (int mb = 0; mb < 4; ++mb)
                #pragma unroll
                for (int r = 0; r < 4; ++r)
                    ko[(size_t)(i0 + mb*16 + quad*4 + r)*DD + (o-32)] = (bf16)acc[mb][nbl][r];
        } else {
            const int c = o - 64;
            #pragma unroll
            for (int mb = 0; mb < 4; ++mb) {
                bf16x4 pk;
                #pragma unroll
                for (int r = 0; r < 4; ++r) pk[r] = (bf16)acc[mb][nbl][r];
                *(bf16x4*)(vo + (size_t)c*SS + i0 + mb*16 + quad*4) = pk;
            }
        }
    }
}

// ------------------------------------------------- attention (key-split, sync-free)
// Block: 64 q x 128 c (c-half), grid 1024. Wave w = (qh = w>>1, kh = w&1):
// queries [i0+32qh, +32), keys [2048kh, +2048), ALL 128 c. P never leaves
// registers: S^T D-frag e[nb][r] (lane ln: q=qb*16+ln, key=16nb+4quad+r) is
// repacked as the PV A-frag by RELABELING MFMA k-slots — slot (quad,ks,j) :=
// key 32ks+16(j>>2)+4quad+(j&3) — and loading V with the SAME permuted key
// order (two bf16x4 at +4quad, +4quad+16). No cross-lane ops, no LDS, no
// barriers in the loop; waves free-run over 32 chunks. kh-pairs sum partial
// o/l via one LDS pass + single barrier at the end.
#define SM_M  16.0f
#define L2E   1.4426950408889634f
#define SM_C  (SM_M * L2E)

__global__ __launch_bounds__(256, 2) void attn_kernel(
    const bf16* __restrict__ qg, const bf16* __restrict__ kg,
    const bf16* __restrict__ vg, float* __restrict__ out)
{
    __shared__ __align__(16) float o_s[64][132];   // [q][c-pad] partials (kh=0)
    __shared__ __align__(16) float l_s[64];

    const int t    = threadIdx.x;
    const int lane = t & 63;
    const int w    = t >> 6;
    const int ln   = lane & 15;
    const int quad = lane >> 4;
    const int qh   = w >> 1;
    const int kh   = w & 1;

    const int bid  = blockIdx.x;
    const int dirb = bid & 7;              // one (dir,b) per XCD
    const int dir  = dirb >> 2;
    const int b    = dirb & 3;
    const int c0   = ((bid >> 3) & 1) * 128;
    const int i0   = (bid >> 4) * 64;

    const bf16* q = qg + ((size_t)dir*BB + b)*SS*DD;
    const bf16* k = kg + ((size_t)(1-dir)*BB + b)*SS*DD;
    const bf16* v = vg + ((size_t)(1-dir)*BB + b)*CC*SS;
    float* op = out + ((size_t)dir*BB + b)*CC*SS;

    // Q B-frags: B[n=q(ln)][k=d(quad*8+)]
    bf16x8 bq[2];
    #pragma unroll
    for (int qb = 0; qb < 2; ++qb)
        bq[qb] = *(const bf16x8*)(q + (size_t)(i0 + qh*32 + qb*16 + ln)*DD + quad*8);

    // K A-frag base: A[m=key(ln)][k=d(quad*8+)], keys offset kh*2048
    const bf16* kbase = k + (size_t)(kh*2048 + ln)*DD + quad*8;
    // V permuted-key base: row c0+ln (+16 per cb), key kh*2048 + 4*quad
    const bf16* vbase = v + (size_t)(c0 + ln)*SS + kh*2048 + quad*4;

    f32x4 o[2][8];
    #pragma unroll
    for (int qb = 0; qb < 2; ++qb)
        #pragma unroll
        for (int cb = 0; cb < 8; ++cb) o[qb][cb] = (f32x4){0.f,0.f,0.f,0.f};
    f32x4 lpq[2] = {(f32x4){0.f,0.f,0.f,0.f}, (f32x4){0.f,0.f,0.f,0.f}};

    bf16x8 kf[4];
    auto loadk = [&](int keyoff) {
        #pragma unroll
        for (int nb = 0; nb < 4; ++nb)
            kf[nb] = *(const bf16x8*)(kbase + (size_t)(keyoff + nb*16)*DD);
    };

    bf16x8 vf[4][2];   // 4-slot cb ring, 2 ks each (permuted key order)
    auto loadv = [&](bf16x8* dst, int cb, int keyoff) {
        const bf16* p0 = vbase + (size_t)cb*16*SS + keyoff;
        #pragma unroll
        for (int ks = 0; ks < 2; ++ks) {
            const bf16x4 lo = *(const bf16x4*)(p0 + ks*32);
            const bf16x4 hi = *(const bf16x4*)(p0 + ks*32 + 16);
            bf16x8 r;
            r[0]=lo[0]; r[1]=lo[1]; r[2]=lo[2]; r[3]=lo[3];
            r[4]=hi[0]; r[5]=hi[1]; r[6]=hi[2]; r[7]=hi[3];
            dst[ks] = r;
        }
    };

    loadk(0);
    #pragma unroll
    for (int cb = 0; cb < 4; ++cb) loadv(vf[cb], cb, 0);

    bf16x8 pa[2][2];

    for (int n = 0; n < 32; ++n) {
        const int ck = n * 64;
        // S^T + softmax + register repack (per qb to cap liveness)
        #pragma unroll
        for (int qb = 0; qb < 2; ++qb) {
            f32x4 s[4];
            #pragma unroll
            for (int nb = 0; nb < 4; ++nb)
                s[nb] = __builtin_amdgcn_mfma_f32_16x16x32_bf16(
                            kf[nb], bq[qb], (f32x4){0.f,0.f,0.f,0.f}, 0, 0, 0);
            float e[4][4];
            #pragma unroll
            for (int nb = 0; nb < 4; ++nb)
                #pragma unroll
                for (int r = 0; r < 4; ++r) {
                    e[nb][r] = exp2f(s[nb][r]*L2E - SM_C);
                    lpq[qb][r] += e[nb][r];
                }
            #pragma unroll
            for (int ks = 0; ks < 2; ++ks) {
                u32x4 pk;
                #pragma unroll
                for (int jp = 0; jp < 4; ++jp)
                    pk[jp] = pack2(e[2*ks + (jp>>1)][2*(jp&1)],
                                   e[2*ks + (jp>>1)][2*(jp&1) + 1]);
                pa[qb][ks] = __builtin_bit_cast(bf16x8, pk);
            }
        }
        // K(n+1) prefetch (wrap at tail: redundant, in-bounds)
        loadk(((n + 1) & 31) * 64);

        // PV + V ring prefetch (4 cb-steps ahead; crosses into chunk n+1)
        #pragma unroll
        for (int cb = 0; cb < 8; ++cb) {
            #pragma unroll
            for (int ks = 0; ks < 2; ++ks)
                #pragma unroll
                for (int qb = 0; qb < 2; ++qb)
                    o[qb][cb] = __builtin_amdgcn_mfma_f32_16x16x32_bf16(
                                    pa[qb][ks], vf[cb & 3][ks], o[qb][cb], 0, 0, 0);
            const int cbn = (cb + 4) & 7;
            const int ckn = (cb < 4) ? ck : ((n + 1) & 31) * 64;
            loadv(vf[cb & 3], cbn, ckn);
        }
    }

    // fold lp over r, reduce over quads (keys 4quad+r+16nb covered per lane)
    float lp[2];
    #pragma unroll
    for (int qb = 0; qb < 2; ++qb) {
        lp[qb] = (lpq[qb][0] + lpq[qb][1]) + (lpq[qb][2] + lpq[qb][3]);
        lp[qb] += __shfl_xor(lp[qb], 16);
        lp[qb] += __shfl_xor(lp[qb], 32);
    }

    // kh-pair reduction: kh=0 stages partials in LDS, kh=1 sums + stores
    if (kh == 0) {
        #pragma unroll
        for (int qb = 0; qb < 2; ++qb)
            #pragma unroll
            for (int cb = 0; cb < 8; ++cb)
                #pragma unroll
                for (int r = 0; r < 4; ++r)
                    o_s[qh*32 + qb*16 + quad*4 + r][cb*16 + ln] = o[qb][cb][r];
        if (quad == 0) {
            l_s[qh*32 + ln]      = lp[0];
            l_s[qh*32 + 16 + ln] = lp[1];
        }
    }
    __syncthreads();
    if (kh == 1) {
        #pragma unroll
        for (int qb = 0; qb < 2; ++qb) {
            // own lp redistributed to this lane's (quad,r) query rows
            f32x4 ri;
            #pragma unroll
            for (int r = 0; r < 4; ++r) {
                const float own = __shfl(lp[qb], quad*4 + r);
                ri[r] = 1.0f / (l_s[qh*32 + qb*16 + quad*4 + r] + own);
            }
            #pragma unroll
            for (int cb = 0; cb < 8; ++cb) {
                const int c = c0 + cb*16 + ln;
                float4 val;
                val.x = (o[qb][cb][0] + o_s[qh*32 + qb*16 + quad*4 + 0][cb*16 + ln]) * ri[0];
                val.y = (o[qb][cb][1] + o_s[qh*32 + qb*16 + quad*4 + 1][cb*16 + ln]) * ri[1];
                val.z = (o[qb][cb][2] + o_s[qh*32 + qb*16 + quad*4 + 2][cb*16 + ln]) * ri[2];
                val.w = (o[qb][cb][3] + o_s[qh*32 + qb*16 + quad*4 + 3][cb*16 + ln]) * ri[3];
                *(float4*)(op + (size_t)c*SS + i0 + qh*32 + qb*16 + quad*4) = val;
            }
        }
    }
}

// ------------------------------------------------- launch
extern "C" void kernel_launch(void* const* d_in, const int* in_sizes, int n_in,
                              void* d_out, int out_size, void* d_ws, size_t ws_size,
                              hipStream_t stream)
{
    const float* x  = (const float*)d_in[0];
    const float* y  = (const float*)d_in[1];
    const float* Wq = (const float*)d_in[2];
    const float* bq = (const float*)d_in[3];
    const float* Wk = (const float*)d_in[4];
    const float* bk = (const float*)d_in[5];
    const float* Wv = (const float*)d_in[6];
    const float* bv = (const float*)d_in[7];
    float* out = (float*)d_out;
    bf16* ws   = (bf16*)d_ws;

    bf16* qw = ws + Q_OFF;
    bf16* kw = ws + K_OFF;
    bf16* vw = ws + V_OFF;
    bf16* wb = ws + WB_OFF;

    convert_w_kernel<<<40,   256, 0, stream>>>(Wq, Wk, Wv, wb);
    proj_all_kernel <<<512,  256, 0, stream>>>(x, y, wb, bq, bk, bv, qw, kw, vw);
    attn_kernel     <<<1024, 256, 0, stream>>>(qw, kw, vw, out);
}

// Round 6
// 407.974 us; speedup vs baseline: 1.4453x; 1.4453x over previous
//
#include <hip/hip_runtime.h>

#define BB 4
#define CC 256
#define DD 32
#define SS 4096

typedef __bf16 bf16;
typedef __bf16 bf16x8 __attribute__((ext_vector_type(8)));
typedef __bf16 bf16x4 __attribute__((ext_vector_type(4)));
typedef float f32x4 __attribute__((ext_vector_type(4)));
typedef unsigned int u32;
typedef u32 u32x4 __attribute__((ext_vector_type(4)));
typedef unsigned short u16;

// workspace layout (bf16 elements):
//  q:  [2][BB][SS][DD]  off 0         (pos-major, 32 d inner)
//  k:  [2][BB][SS][DD]  off 1048576
//  v:  [2][BB][...]     off 2097152   MFMA-B-frag order: element V[c][key]
//       at ((2n+ks)*256+c)*32 + quad*8 + b4*4 + lo, where key =
//       64n + 32ks + 16*b4 + 4*quad + lo  (k-slot relabeling, see attn)
//  wb: [320][CC]        off 10485760  (bf16 Wq|Wk|Wv stacked)
#define Q_OFF  0
#define K_OFF  1048576
#define V_OFF  2097152
#define WB_OFF 10485760

static __device__ __forceinline__ u32 pack2(float lo, float hi) {
    bf16 a = (bf16)lo, b = (bf16)hi;
    u16 ua = __builtin_bit_cast(u16, a), ub = __builtin_bit_cast(u16, b);
    return (u32)ua | ((u32)ub << 16);
}

// LDS-only barrier: drain ds ops, sync, but let global loads stay in flight
static __device__ __forceinline__ void bar_lds() {
    asm volatile("s_waitcnt lgkmcnt(0)" ::: "memory");
    __builtin_amdgcn_s_barrier();
    asm volatile("" ::: "memory");
}

// ------------------------------------------------- W fp32 -> bf16 [320][256]
__global__ __launch_bounds__(256) void convert_w_kernel(
    const float* __restrict__ Wq, const float* __restrict__ Wk,
    const float* __restrict__ Wv, bf16* __restrict__ wb)
{
    const int gid = blockIdx.x*256 + threadIdx.x;    // 40 blocks -> 10240
    const int idx = gid*8;
    const int o = idx >> 8, cc = idx & 255;
    const float* row = (o < 32) ? (Wq + (size_t)o*CC)
                     : (o < 64) ? (Wk + (size_t)(o-32)*CC)
                                : (Wv + (size_t)(o-64)*CC);
    const float4 a = *(const float4*)(row + cc);
    const float4 c = *(const float4*)(row + cc + 4);
    bf16x8 pk;
    pk[0]=(bf16)a.x; pk[1]=(bf16)a.y; pk[2]=(bf16)a.z; pk[3]=(bf16)a.w;
    pk[4]=(bf16)c.x; pk[5]=(bf16)c.y; pk[6]=(bf16)c.z; pk[7]=(bf16)c.w;
    *(bf16x8*)(wb + idx) = pk;
}

// ------------------------------------------------- fused q,k,v projection (MFMA)
// C[pos][o] = sum_cc X[cc][pos]*W[o][cc] + bias;  o: 0-31 q, 32-63 k, 64-319 v
// V is written in attn's MFMA-B-fragment order (see workspace comment).
__global__ __launch_bounds__(256, 2) void proj_all_kernel(
    const float* __restrict__ x, const float* __restrict__ y,
    const bf16* __restrict__ wb,
    const float* __restrict__ bq, const float* __restrict__ bk,
    const float* __restrict__ bv,
    bf16* __restrict__ qout, bf16* __restrict__ kout, bf16* __restrict__ vout)
{
    // xT: [2][64 pos][40 bf16] (row 80 B, 16B-aligned)
    __shared__ __align__(16) char smem[2*5120];
    bf16* xT  = (bf16*)smem;
    u32*  xTw = (u32*)smem;

    const int t    = threadIdx.x;
    const int lane = t & 63;
    const int w    = t >> 6;
    const int ln   = lane & 15;
    const int quad = lane >> 4;

    const int bid  = blockIdx.x;
    const int dirb = bid & 7;
    const int src  = dirb >> 2;
    const int b    = dirb & 3;
    const int i0   = (bid >> 3) * 64;
    const float* in = src ? y : x;
    const float* xbase = in + (size_t)b*CC*SS + i0;

    const int cp = t >> 4;            // cc-pair 0..15 -> cc {2cp, 2cp+1}
    const int pq = (t & 15) * 4;      // pos 0..60

    float bias[5];
    #pragma unroll
    for (int nbl = 0; nbl < 5; ++nbl) {
        const int o = 80*w + nbl*16 + ln;
        bias[nbl] = (o < 32) ? bq[o] : (o < 64) ? bk[o-32] : bv[o-64];
    }
    f32x4 acc[4][5];
    #pragma unroll
    for (int mb = 0; mb < 4; ++mb)
        #pragma unroll
        for (int nbl = 0; nbl < 5; ++nbl)
            acc[mb][nbl] = (f32x4){bias[nbl], bias[nbl], bias[nbl], bias[nbl]};

    const bf16* wrow = wb + (size_t)(80*w + ln)*CC + quad*8;
    bf16x8 bf[5];
    #pragma unroll
    for (int nbl = 0; nbl < 5; ++nbl)
        bf[nbl] = *(const bf16x8*)(wrow + (size_t)nbl*16*CC);

    // stage chunk 0 into buf0
    {
        const float* r0 = xbase + (size_t)(2*cp)*SS + pq;
        const float4 a0 = *(const float4*)r0;
        const float4 a1 = *(const float4*)(r0 + SS);
        xTw[(pq+0)*20 + cp] = pack2(a0.x, a1.x);
        xTw[(pq+1)*20 + cp] = pack2(a0.y, a1.y);
        xTw[(pq+2)*20 + cp] = pack2(a0.z, a1.z);
        xTw[(pq+3)*20 + cp] = pack2(a0.w, a1.w);
    }
    // prefetch chunk 1 into regs
    float4 a0, a1;
    {
        const float* r1 = xbase + (size_t)(32 + 2*cp)*SS + pq;
        a0 = *(const float4*)r1;
        a1 = *(const float4*)(r1 + SS);
    }
    bar_lds();

    for (int n = 0; n < 8; ++n) {
        bf16x8 af[4];
        #pragma unroll
        for (int mb = 0; mb < 4; ++mb)
            af[mb] = *(const bf16x8*)(xT + (n&1)*2560 + (mb*16 + ln)*40 + quad*8);
        // write prefetched chunk n+1 into other buffer
        if (n < 7) {
            u32* dst = xTw + ((n+1)&1)*1280;
            dst[(pq+0)*20 + cp] = pack2(a0.x, a1.x);
            dst[(pq+1)*20 + cp] = pack2(a0.y, a1.y);
            dst[(pq+2)*20 + cp] = pack2(a0.z, a1.z);
            dst[(pq+3)*20 + cp] = pack2(a0.w, a1.w);
        }
        // prefetch chunk n+2 regs (wrap keeps loads in-bounds; redundant at tail)
        {
            const int cc2 = ((n+2)*32) & 255;
            const float* r2 = xbase + (size_t)(cc2 + 2*cp)*SS + pq;
            a0 = *(const float4*)r2;
            a1 = *(const float4*)(r2 + SS);
        }
        #pragma unroll
        for (int mb = 0; mb < 4; ++mb)
            #pragma unroll
            for (int nbl = 0; nbl < 5; ++nbl)
                acc[mb][nbl] = __builtin_amdgcn_mfma_f32_16x16x32_bf16(
                                   af[mb], bf[nbl], acc[mb][nbl], 0, 0, 0);
        // prefetch next W chunk
        const int ccn = ((n+1)*32) & 255;
        #pragma unroll
        for (int nbl = 0; nbl < 5; ++nbl)
            bf[nbl] = *(const bf16x8*)(wrow + (size_t)nbl*16*CC + ccn);
        bar_lds();
    }

    bf16* qo = qout + (size_t)(src*BB + b)*SS*DD;
    bf16* ko = kout + (size_t)(src*BB + b)*SS*DD;
    bf16* vo = vout + (size_t)(src*BB + b)*CC*SS;
    const int n0 = i0 >> 6;
    #pragma unroll
    for (int nbl = 0; nbl < 5; ++nbl) {
        const int o = 80*w + nbl*16 + ln;
        if (o < 32) {
            #pragma unroll
            for (int mb = 0; mb < 4; ++mb)
                #pragma unroll
                for (int r = 0; r < 4; ++r)
                    qo[(size_t)(i0 + mb*16 + quad*4 + r)*DD + o] = (bf16)acc[mb][nbl][r];
        } else if (o < 64) {
            #pragma unroll
            for (int mb = 0; mb < 4; ++mb)
                #pragma unroll
                for (int r = 0; r < 4; ++r)
                    ko[(size_t)(i0 + mb*16 + quad*4 + r)*DD + (o-32)] = (bf16)acc[mb][nbl][r];
        } else {
            const int c = o - 64;
            // pos = i0 + mb*16 + quad*4 + r -> n=n0, ks=mb>>1, b4=mb&1,
            // quad-field=quad, lo=r -> contiguous bf16x4 store
            #pragma unroll
            for (int mb = 0; mb < 4; ++mb) {
                bf16x4 pk;
                #pragma unroll
                for (int r = 0; r < 4; ++r) pk[r] = (bf16)acc[mb][nbl][r];
                *(bf16x4*)(vo + ((size_t)(2*n0 + (mb>>1))*256 + c)*32
                              + quad*8 + (mb&1)*4) = pk;
            }
        }
    }
}

// ------------------------------------------------- attention (wave-private, sync-free)
// Block: 64 q x 256 c, grid 512. Wave w = (qh=w>>1, kh=w&1): privately owns
// queries [i0+32qh,+32) x ALL 256 c x keys [2048kh,+2048). P never leaves
// registers: S^T D-frag e[nb][r] (lane ln: q=col, key=16nb+4quad+r) repacked
// as PV A-frag by k-slot relabeling (slot (quad,ks,j) := key 32ks+16(j>>2)+
// 4quad+(j&3)); V is PRE-PERMUTED in the workspace to match, so each B-frag
// is ONE coalesced 16-B load (R5's failure was 8-B scattered V gathers).
// Zero LDS / zero sync in the loop -> waves free-run, load bursts de-convoy.
// V ring depth 8 (~390 cy cover); K prefetched one chunk ahead. kh pairs
// reduce o/l via a 2-pass LDS epilogue (37 KB).
#define L2E   1.4426950408889634f
#define SM_C  (16.0f * L2E)

__global__ __launch_bounds__(256, 2) void attn_kernel(
    const bf16* __restrict__ qg, const bf16* __restrict__ kg,
    const bf16* __restrict__ vg, float* __restrict__ out)
{
    __shared__ __align__(16) float o_s[256][36];   // [c][32 q rows + pad]
    __shared__ float l_s[2][64];                   // [kh][q]

    const int t    = threadIdx.x;
    const int lane = t & 63;
    const int w    = t >> 6;
    const int ln   = lane & 15;
    const int quad = lane >> 4;
    const int qh   = w >> 1;
    const int kh   = w & 1;

    const int bid  = blockIdx.x;
    const int dirb = bid & 7;              // one (dir,b) per XCD
    const int dir  = dirb >> 2;
    const int b    = dirb & 3;
    const int i0   = (bid >> 3) * 64;

    const bf16* q = qg + ((size_t)dir*BB + b)*SS*DD;
    const bf16* k = kg + ((size_t)(1-dir)*BB + b)*SS*DD;
    const bf16* v = vg + ((size_t)(1-dir)*BB + b)*CC*SS;
    float* op = out + ((size_t)dir*BB + b)*CC*SS;

    // Q B-frags: B[n=q(ln)][k=d(quad*8+)]
    const bf16x8 bq0 = *(const bf16x8*)(q + (size_t)(i0 + qh*32 +      ln)*DD + quad*8);
    const bf16x8 bq1 = *(const bf16x8*)(q + (size_t)(i0 + qh*32 + 16 + ln)*DD + quad*8);

    // K A-frag base: A[m=key(ln)][k=d(quad*8+)], keys offset kh*2048
    const bf16* kbase = k + (size_t)(kh*2048 + ln)*DD + quad*8;
    // V (pre-permuted layout): lane's fragment for (nn,ks,cb) is 16 B at
    // vlane + (2nn+ks)*8192 + cb*512
    const bf16* vlane = v + (size_t)kh*524288 + ln*32 + quad*8;

    f32x4 o[2][16];
    #pragma unroll
    for (int qb = 0; qb < 2; ++qb)
        #pragma unroll
        for (int cb = 0; cb < 16; ++cb) o[qb][cb] = (f32x4){0.f,0.f,0.f,0.f};
    f32x4 lpq[2] = {(f32x4){0.f,0.f,0.f,0.f}, (f32x4){0.f,0.f,0.f,0.f}};

    bf16x8 kf[4];
    #pragma unroll
    for (int nb = 0; nb < 4; ++nb)
        kf[nb] = *(const bf16x8*)(kbase + (size_t)(nb*16)*DD);

    bf16x8 vf[8];      // ring: slot = step&7, step = cb*2+ks, 8-step prefetch
    #pragma unroll
    for (int st = 0; st < 8; ++st)
        vf[st] = *(const bf16x8*)(vlane + (st&1)*8192 + (st>>1)*512);

    bf16x8 pa[2][2];

    for (int nn = 0; nn < 32; ++nn) {
        // S^T + softmax + register repack (per qb to cap liveness)
        #pragma unroll
        for (int qb = 0; qb < 2; ++qb) {
            const bf16x8 bqq = qb ? bq1 : bq0;
            f32x4 s[4];
            #pragma unroll
            for (int nb = 0; nb < 4; ++nb)
                s[nb] = __builtin_amdgcn_mfma_f32_16x16x32_bf16(
                            kf[nb], bqq, (f32x4){0.f,0.f,0.f,0.f}, 0, 0, 0);
            float e[4][4];
            #pragma unroll
            for (int nb = 0; nb < 4; ++nb)
                #pragma unroll
                for (int r = 0; r < 4; ++r) {
                    e[nb][r] = exp2f(s[nb][r]*L2E - SM_C);
                    lpq[qb][r] += e[nb][r];
                }
            #pragma unroll
            for (int ks = 0; ks < 2; ++ks) {
                u32x4 pk;
                #pragma unroll
                for (int jp = 0; jp < 4; ++jp)
                    pk[jp] = pack2(e[2*ks + (jp>>1)][2*(jp&1)],
                                   e[2*ks + (jp>>1)][2*(jp&1) + 1]);
                pa[qb][ks] = __builtin_bit_cast(bf16x8, pk);
            }
        }
        // K(nn+1) prefetch (wrap at tail: redundant, in-bounds)
        {
            const int koff = ((nn + 1) & 31) * 64;
            #pragma unroll
            for (int nb = 0; nb < 4; ++nb)
                kf[nb] = *(const bf16x8*)(kbase + (size_t)(koff + nb*16)*DD);
        }

        // PV: 32 steps (cb,ks); consume vf[st&7], reload with step st+8
        const bf16* vA = vlane + (size_t)nn * 16384;
        const bf16* vB = vlane + (size_t)((nn + 1) & 31) * 16384;
        #pragma unroll
        for (int st = 0; st < 32; ++st) {
            const int cb = st >> 1, ks = st & 1;
            o[0][cb] = __builtin_amdgcn_mfma_f32_16x16x32_bf16(
                           pa[0][ks], vf[st & 7], o[0][cb], 0, 0, 0);
            o[1][cb] = __builtin_amdgcn_mfma_f32_16x16x32_bf16(
                           pa[1][ks], vf[st & 7], o[1][cb], 0, 0, 0);
            const int st8 = st + 8;
            const bf16* vsrc = (st8 < 32)
                ? (vA + (st8 & 1)*8192 + (st8 >> 1)*512)
                : (vB + (st8 & 1)*8192 + ((st8 - 32) >> 1)*512);
            vf[st & 7] = *(const bf16x8*)vsrc;
        }
    }

    // per-wave l: lane ln holds q-col, keys {16nb+4quad+r} -> fold r, quads
    float lp0 = (lpq[0][0] + lpq[0][1]) + (lpq[0][2] + lpq[0][3]);
    float lp1 = (lpq[1][0] + lpq[1][1]) + (lpq[1][2] + lpq[1][3]);
    lp0 += __shfl_xor(lp0, 16); lp0 += __shfl_xor(lp0, 32);
    lp1 += __shfl_xor(lp1, 16); lp1 += __shfl_xor(lp1, 32);
    if (quad == 0) {
        l_s[kh][qh*32 +      ln] = lp0;
        l_s[kh][qh*32 + 16 + ln] = lp1;
    }

    // kh-pair reduction, 2 passes (qb) through 32-row o_s
    #pragma unroll
    for (int qb = 0; qb < 2; ++qb) {
        if (kh == 0) {
            #pragma unroll
            for (int cb = 0; cb < 16; ++cb)
                *(f32x4*)&o_s[cb*16 + ln][qh*16 + quad*4] = o[qb][cb];
        }
        __syncthreads();
        if (kh == 1) {
            const int q0 = qh*32 + qb*16 + quad*4;
            f32x4 ri;
            #pragma unroll
            for (int r = 0; r < 4; ++r)
                ri[r] = 1.0f / (l_s[0][q0 + r] + l_s[1][q0 + r]);
            #pragma unroll
            for (int cb = 0; cb < 16; ++cb) {
                const int c = cb*16 + ln;
                const f32x4 part = *(const f32x4*)&o_s[c][qh*16 + quad*4];
                float4 val;
                val.x = (o[qb][cb][0] + part[0]) * ri[0];
                val.y = (o[qb][cb][1] + part[1]) * ri[1];
                val.z = (o[qb][cb][2] + part[2]) * ri[2];
                val.w = (o[qb][cb][3] + part[3]) * ri[3];
                *(float4*)(op + (size_t)c*SS + i0 + q0) = val;
            }
        }
        __syncthreads();
    }
}

// ------------------------------------------------- launch
extern "C" void kernel_launch(void* const* d_in, const int* in_sizes, int n_in,
                              void* d_out, int out_size, void* d_ws, size_t ws_size,
                              hipStream_t stream)
{
    const float* x  = (const float*)d_in[0];
    const float* y  = (const float*)d_in[1];
    const float* Wq = (const float*)d_in[2];
    const float* bq = (const float*)d_in[3];
    const float* Wk = (const float*)d_in[4];
    const float* bk = (const float*)d_in[5];
    const float* Wv = (const float*)d_in[6];
    const float* bv = (const float*)d_in[7];
    float* out = (float*)d_out;
    bf16* ws   = (bf16*)d_ws;

    bf16* qw = ws + Q_OFF;
    bf16* kw = ws + K_OFF;
    bf16* vw = ws + V_OFF;
    bf16* wb = ws + WB_OFF;

    convert_w_kernel<<<40,  256, 0, stream>>>(Wq, Wk, Wv, wb);
    proj_all_kernel <<<512, 256, 0, stream>>>(x, y, wb, bq, bk, bv, qw, kw, vw);
    attn_kernel     <<<512, 256, 0, stream>>>(qw, kw, vw, out);
}

// Round 7
// 207.219 us; speedup vs baseline: 2.8456x; 1.9688x over previous
//
#include <hip/hip_runtime.h>

#define BB 4
#define CC 256
#define DD 32
#define SS 4096

typedef __bf16 bf16;
typedef __bf16 bf16x8 __attribute__((ext_vector_type(8)));
typedef __bf16 bf16x4 __attribute__((ext_vector_type(4)));
typedef float f32x4 __attribute__((ext_vector_type(4)));
typedef unsigned int u32;
typedef u32 u32x4 __attribute__((ext_vector_type(4)));
typedef unsigned short u16;

// workspace layout (bf16 elements):
//  q:  [2][BB][SS][DD]  off 0         (pos-major, 32 d inner)
//  k:  [2][BB][SS][DD]  off 1048576
//  v:  [2][BB][...]     off 2097152   chunked B-frag order: V[c][key] at
//       (2*(key>>6) + ks)*8192 + (c>>4)*512 + (quadf*16 + (c&15))*8 + j
//       where kk=key&63, ks=kk>>5, quadf=(kk>>2)&3, j=((kk>>4)&1)*4 + (kk&3)
//       -> each 1 KB fragment is lane-contiguous (lane*16 B), each 32 KB
//       chunk (64 keys x 256 c) is fully contiguous for linear LDS staging.
//  wb: [320][CC]        off 10485760  (bf16 Wq|Wk|Wv stacked)
#define Q_OFF  0
#define K_OFF  1048576
#define V_OFF  2097152
#define WB_OFF 10485760
#define CH_ELEM 16384   // elements per 64-key V chunk (32 KB)

static __device__ __forceinline__ u32 pack2(float lo, float hi) {
    bf16 a = (bf16)lo, b = (bf16)hi;
    u16 ua = __builtin_bit_cast(u16, a), ub = __builtin_bit_cast(u16, b);
    return (u32)ua | ((u32)ub << 16);
}

// LDS-only barrier: drain ds ops, sync, but let global loads stay in flight
static __device__ __forceinline__ void bar_lds() {
    asm volatile("s_waitcnt lgkmcnt(0)" ::: "memory");
    __builtin_amdgcn_s_barrier();
    asm volatile("" ::: "memory");
}

// staged-buffer barrier: wait until only the 12 newest VMEM ops (next chunk's
// 8 staging + next K prefetch 4) remain in flight -> current chunk's staging
// complete, pipeline never drained (T4 counted-vmcnt).
static __device__ __forceinline__ void bar_vm12() {
    asm volatile("s_waitcnt vmcnt(12)" ::: "memory");
    __builtin_amdgcn_s_barrier();
    asm volatile("" ::: "memory");
}
static __device__ __forceinline__ void bar_plain() {
    asm volatile("" ::: "memory");
    __builtin_amdgcn_s_barrier();
    asm volatile("" ::: "memory");
}

// ------------------------------------------------- W fp32 -> bf16 [320][256]
__global__ __launch_bounds__(256) void convert_w_kernel(
    const float* __restrict__ Wq, const float* __restrict__ Wk,
    const float* __restrict__ Wv, bf16* __restrict__ wb)
{
    const int gid = blockIdx.x*256 + threadIdx.x;    // 40 blocks -> 10240
    const int idx = gid*8;
    const int o = idx >> 8, cc = idx & 255;
    const float* row = (o < 32) ? (Wq + (size_t)o*CC)
                     : (o < 64) ? (Wk + (size_t)(o-32)*CC)
                                : (Wv + (size_t)(o-64)*CC);
    const float4 a = *(const float4*)(row + cc);
    const float4 c = *(const float4*)(row + cc + 4);
    bf16x8 pk;
    pk[0]=(bf16)a.x; pk[1]=(bf16)a.y; pk[2]=(bf16)a.z; pk[3]=(bf16)a.w;
    pk[4]=(bf16)c.x; pk[5]=(bf16)c.y; pk[6]=(bf16)c.z; pk[7]=(bf16)c.w;
    *(bf16x8*)(wb + idx) = pk;
}

// ------------------------------------------------- fused q,k,v projection (MFMA)
// C[pos][o] = sum_cc X[cc][pos]*W[o][cc] + bias;  o: 0-31 q, 32-63 k, 64-319 v
// V written in attn's chunked B-frag order (see workspace comment).
__global__ __launch_bounds__(256, 2) void proj_all_kernel(
    const float* __restrict__ x, const float* __restrict__ y,
    const bf16* __restrict__ wb,
    const float* __restrict__ bq, const float* __restrict__ bk,
    const float* __restrict__ bv,
    bf16* __restrict__ qout, bf16* __restrict__ kout, bf16* __restrict__ vout)
{
    // xT: [2][64 pos][40 bf16] (row 80 B, 16B-aligned)
    __shared__ __align__(16) char smem[2*5120];
    bf16* xT  = (bf16*)smem;
    u32*  xTw = (u32*)smem;

    const int t    = threadIdx.x;
    const int lane = t & 63;
    const int w    = t >> 6;
    const int ln   = lane & 15;
    const int quad = lane >> 4;

    const int bid  = blockIdx.x;
    const int dirb = bid & 7;
    const int src  = dirb >> 2;
    const int b    = dirb & 3;
    const int i0   = (bid >> 3) * 64;
    const float* in = src ? y : x;
    const float* xbase = in + (size_t)b*CC*SS + i0;

    const int cp = t >> 4;            // cc-pair 0..15 -> cc {2cp, 2cp+1}
    const int pq = (t & 15) * 4;      // pos 0..60

    float bias[5];
    #pragma unroll
    for (int nbl = 0; nbl < 5; ++nbl) {
        const int o = 80*w + nbl*16 + ln;
        bias[nbl] = (o < 32) ? bq[o] : (o < 64) ? bk[o-32] : bv[o-64];
    }
    f32x4 acc[4][5];
    #pragma unroll
    for (int mb = 0; mb < 4; ++mb)
        #pragma unroll
        for (int nbl = 0; nbl < 5; ++nbl)
            acc[mb][nbl] = (f32x4){bias[nbl], bias[nbl], bias[nbl], bias[nbl]};

    const bf16* wrow = wb + (size_t)(80*w + ln)*CC + quad*8;
    bf16x8 bf[5];
    #pragma unroll
    for (int nbl = 0; nbl < 5; ++nbl)
        bf[nbl] = *(const bf16x8*)(wrow + (size_t)nbl*16*CC);

    // stage chunk 0 into buf0
    {
        const float* r0 = xbase + (size_t)(2*cp)*SS + pq;
        const float4 a0 = *(const float4*)r0;
        const float4 a1 = *(const float4*)(r0 + SS);
        xTw[(pq+0)*20 + cp] = pack2(a0.x, a1.x);
        xTw[(pq+1)*20 + cp] = pack2(a0.y, a1.y);
        xTw[(pq+2)*20 + cp] = pack2(a0.z, a1.z);
        xTw[(pq+3)*20 + cp] = pack2(a0.w, a1.w);
    }
    // prefetch chunk 1 into regs
    float4 a0, a1;
    {
        const float* r1 = xbase + (size_t)(32 + 2*cp)*SS + pq;
        a0 = *(const float4*)r1;
        a1 = *(const float4*)(r1 + SS);
    }
    bar_lds();

    for (int n = 0; n < 8; ++n) {
        bf16x8 af[4];
        #pragma unroll
        for (int mb = 0; mb < 4; ++mb)
            af[mb] = *(const bf16x8*)(xT + (n&1)*2560 + (mb*16 + ln)*40 + quad*8);
        // write prefetched chunk n+1 into other buffer
        if (n < 7) {
            u32* dst = xTw + ((n+1)&1)*1280;
            dst[(pq+0)*20 + cp] = pack2(a0.x, a1.x);
            dst[(pq+1)*20 + cp] = pack2(a0.y, a1.y);
            dst[(pq+2)*20 + cp] = pack2(a0.z, a1.z);
            dst[(pq+3)*20 + cp] = pack2(a0.w, a1.w);
        }
        // prefetch chunk n+2 regs (wrap keeps loads in-bounds; redundant at tail)
        {
            const int cc2 = ((n+2)*32) & 255;
            const float* r2 = xbase + (size_t)(cc2 + 2*cp)*SS + pq;
            a0 = *(const float4*)r2;
            a1 = *(const float4*)(r2 + SS);
        }
        #pragma unroll
        for (int mb = 0; mb < 4; ++mb)
            #pragma unroll
            for (int nbl = 0; nbl < 5; ++nbl)
                acc[mb][nbl] = __builtin_amdgcn_mfma_f32_16x16x32_bf16(
                                   af[mb], bf[nbl], acc[mb][nbl], 0, 0, 0);
        // prefetch next W chunk
        const int ccn = ((n+1)*32) & 255;
        #pragma unroll
        for (int nbl = 0; nbl < 5; ++nbl)
            bf[nbl] = *(const bf16x8*)(wrow + (size_t)nbl*16*CC + ccn);
        bar_lds();
    }

    bf16* qo = qout + (size_t)(src*BB + b)*SS*DD;
    bf16* ko = kout + (size_t)(src*BB + b)*SS*DD;
    bf16* vo = vout + (size_t)(src*BB + b)*CC*SS;
    const int n0 = i0 >> 6;
    #pragma unroll
    for (int nbl = 0; nbl < 5; ++nbl) {
        const int o = 80*w + nbl*16 + ln;
        if (o < 32) {
            #pragma unroll
            for (int mb = 0; mb < 4; ++mb)
                #pragma unroll
                for (int r = 0; r < 4; ++r)
                    qo[(size_t)(i0 + mb*16 + quad*4 + r)*DD + o] = (bf16)acc[mb][nbl][r];
        } else if (o < 64) {
            #pragma unroll
            for (int mb = 0; mb < 4; ++mb)
                #pragma unroll
                for (int r = 0; r < 4; ++r)
                    ko[(size_t)(i0 + mb*16 + quad*4 + r)*DD + (o-32)] = (bf16)acc[mb][nbl][r];
        } else {
            const int c = o - 64;
            const int cb = c >> 4, cl = c & 15;
            // pos = i0+mb*16+quad*4+r -> chunk n0, ks=mb>>1, j=(mb&1)*4+r,
            // quadf=quad -> contiguous bf16x4 store within lane's 16B slot
            #pragma unroll
            for (int mb = 0; mb < 4; ++mb) {
                bf16x4 pk;
                #pragma unroll
                for (int r = 0; r < 4; ++r) pk[r] = (bf16)acc[mb][nbl][r];
                *(bf16x4*)(vo + (size_t)(2*n0 + (mb>>1))*8192 + cb*512
                              + (quad*16 + cl)*8 + (mb&1)*4) = pk;
            }
        }
    }
}

// ------------------------------------------------- attention (LDS-staged V, private P)
// Block: 64 q x 256 c, grid 512 (2 blocks/CU). Wave w privately owns queries
// [i0+16w,+16) x all 256 c x all keys: S^T+softmax+P all in registers (verified
// pack + k-slot relabel), NO cross-wave reduction. V is delivered by bulk
// async DMA: 32 KB chunk (64 keys x 256 c, pre-permuted lane-contiguous)
// double-buffered in LDS via global_load_lds(16B) — zero VGPR cost, so the
// R6 o/vf register tension disappears. Counted vmcnt(12) at the chunk barrier
// keeps the next chunk's staging + K prefetch in flight (never drains).
// Per-chunk: S^T(n+1) 4 MFMA + softmax (overlap other wave's PV) | barrier |
// 32 ds_read_b128 (conflict-free) + 32 PV MFMA | barrier | stage(n+2).
#define L2E   1.4426950408889634f
#define SM_C  (16.0f * L2E)

__global__ __launch_bounds__(256, 2) void attn_kernel(
    const bf16* __restrict__ qg, const bf16* __restrict__ kg,
    const bf16* __restrict__ vg, float* __restrict__ out)
{
    __shared__ __align__(16) char vsm[2*32768];   // V chunk double buffer

    const int t    = threadIdx.x;
    const int lane = t & 63;
    const int w    = t >> 6;
    const int ln   = lane & 15;
    const int quad = lane >> 4;

    const int bid  = blockIdx.x;
    const int dirb = bid & 7;              // one (dir,b) per XCD -> V L2-resident
    const int dir  = dirb >> 2;
    const int b    = dirb & 3;
    const int i0   = (bid >> 3) * 64;

    const bf16* q = qg + ((size_t)dir*BB + b)*SS*DD;
    const bf16* k = kg + ((size_t)(1-dir)*BB + b)*SS*DD;
    const bf16* v = vg + ((size_t)(1-dir)*BB + b)*(size_t)CC*SS;
    float* op = out + ((size_t)dir*BB + b)*(size_t)CC*SS;

    // Q B-frag: B[n=q(ln)][k=d(quad*8+)] — wave's 16 queries
    const bf16x8 bq = *(const bf16x8*)(q + (size_t)(i0 + w*16 + ln)*DD + quad*8);
    // K A-frag base: A[m=key(ln)][k=d(quad*8+)]
    const bf16* kbase = k + (size_t)ln*DD + quad*8;
    // staging: thread t copies 8x16B, linear; global elem off = w*512+lane*8+j*2048
    const bf16* vstage = v + w*512 + lane*8;
    char* lds0 = vsm + w*1024;

    f32x4 o[16];
    #pragma unroll
    for (int cb = 0; cb < 16; ++cb) o[cb] = (f32x4){0.f,0.f,0.f,0.f};
    f32x4 lpq = (f32x4){0.f,0.f,0.f,0.f};

    bf16x8 kf[4];
    #pragma unroll
    for (int nb = 0; nb < 4; ++nb)
        kf[nb] = *(const bf16x8*)(kbase + (size_t)(nb*16)*DD);

    #define STAGE(ch, buf) do {                                               \
        const bf16* gp_ = vstage + (size_t)(ch)*CH_ELEM;                      \
        char* lp_ = lds0 + (buf)*32768;                                       \
        _Pragma("unroll")                                                     \
        for (int j = 0; j < 8; ++j)                                           \
            __builtin_amdgcn_global_load_lds(                                 \
                (const __attribute__((address_space(1))) void*)(gp_ + j*2048),\
                (__attribute__((address_space(3))) void*)(lp_ + j*4096),      \
                16, 0, 0);                                                    \
    } while (0)

    #define SMAX(sarr, pa) do {                                               \
        float e_[4][4];                                                       \
        _Pragma("unroll")                                                     \
        for (int nb = 0; nb < 4; ++nb)                                        \
            _Pragma("unroll")                                                 \
            for (int r = 0; r < 4; ++r) {                                     \
                e_[nb][r] = exp2f((sarr)[nb][r]*L2E - SM_C);                   \
                lpq[r] += e_[nb][r];                                          \
            }                                                                 \
        _Pragma("unroll")                                                     \
        for (int ks = 0; ks < 2; ++ks) {                                      \
            u32x4 pk_;                                                        \
            _Pragma("unroll")                                                 \
            for (int jp = 0; jp < 4; ++jp)                                    \
                pk_[jp] = pack2(e_[2*ks + (jp>>1)][2*(jp&1)],                 \
                                e_[2*ks + (jp>>1)][2*(jp&1) + 1]);            \
            (pa)[ks] = __builtin_bit_cast(bf16x8, pk_);                       \
        }                                                                     \
    } while (0)

    bf16x8 paA[2], paB[2];
    // prologue: S^T(0) -> paA; stage chunks 0,1; kf <- K(1)
    {
        f32x4 s[4];
        #pragma unroll
        for (int nb = 0; nb < 4; ++nb)
            s[nb] = __builtin_amdgcn_mfma_f32_16x16x32_bf16(
                        kf[nb], bq, (f32x4){0.f,0.f,0.f,0.f}, 0, 0, 0);
        STAGE(0, 0);
        STAGE(1, 1);
        #pragma unroll
        for (int nb = 0; nb < 4; ++nb)
            kf[nb] = *(const bf16x8*)(kbase + (size_t)(64 + nb*16)*DD);
        SMAX(s, paA);
    }

    for (int n = 0; n < 64; ++n) {
        // S^T(n+1) (kf = K(n+1)), kf <- K(n+2), softmax -> paB  [all private]
        if (n < 63) {
            f32x4 s[4];
            #pragma unroll
            for (int nb = 0; nb < 4; ++nb)
                s[nb] = __builtin_amdgcn_mfma_f32_16x16x32_bf16(
                            kf[nb], bq, (f32x4){0.f,0.f,0.f,0.f}, 0, 0, 0);
            const int j2 = ((n + 2) & 63) * 64;
            #pragma unroll
            for (int nb = 0; nb < 4; ++nb)
                kf[nb] = *(const bf16x8*)(kbase + (size_t)(j2 + nb*16)*DD);
            SMAX(s, paB);
        }

        // staging(n) complete everywhere; 12 newest (stage n+1 + K n+2) stay
        bar_vm12();

        // PV(n): 32 conflict-free ds_read_b128 + 32 MFMA, all per-wave
        const char* bufp = vsm + (n & 1)*32768;
        __builtin_amdgcn_s_setprio(1);
        #pragma unroll
        for (int st = 0; st < 32; ++st) {
            const int cb = st & 15;          // ks = st>>4
            const bf16x8 vfr = *(const bf16x8*)(bufp + st*1024 + lane*16);
            o[cb] = __builtin_amdgcn_mfma_f32_16x16x32_bf16(
                        paA[st >> 4], vfr, o[cb], 0, 0, 0);
        }
        __builtin_amdgcn_s_setprio(0);

        bar_plain();                 // all waves done reading buf[n&1]
        STAGE((n + 2) & 63, n & 1);  // refill just-freed buffer (2 iters ahead)

        paA[0] = paB[0];
        paA[1] = paB[1];
    }

    // l per lane: q=ln, keys {16nb+4quad+r} -> fold r, reduce quad copies
    float lp = (lpq[0] + lpq[1]) + (lpq[2] + lpq[3]);
    lp += __shfl_xor(lp, 16);
    lp += __shfl_xor(lp, 32);
    f32x4 ri;
    #pragma unroll
    for (int r = 0; r < 4; ++r)
        ri[r] = 1.0f / __shfl(lp, quad*4 + r);

    // epilogue: fully private, direct stores (row q = i0+w*16+quad*4+r, col c)
    #pragma unroll
    for (int cb = 0; cb < 16; ++cb) {
        const int c = cb*16 + ln;
        float4 val = make_float4(o[cb][0]*ri[0], o[cb][1]*ri[1],
                                 o[cb][2]*ri[2], o[cb][3]*ri[3]);
        *(float4*)(op + (size_t)c*SS + i0 + w*16 + quad*4) = val;
    }
    #undef STAGE
    #undef SMAX
}

// ------------------------------------------------- launch
extern "C" void kernel_launch(void* const* d_in, const int* in_sizes, int n_in,
                              void* d_out, int out_size, void* d_ws, size_t ws_size,
                              hipStream_t stream)
{
    const float* x  = (const float*)d_in[0];
    const float* y  = (const float*)d_in[1];
    const float* Wq = (const float*)d_in[2];
    const float* bq = (const float*)d_in[3];
    const float* Wk = (const float*)d_in[4];
    const float* bk = (const float*)d_in[5];
    const float* Wv = (const float*)d_in[6];
    const float* bv = (const float*)d_in[7];
    float* out = (float*)d_out;
    bf16* ws   = (bf16*)d_ws;

    bf16* qw = ws + Q_OFF;
    bf16* kw = ws + K_OFF;
    bf16* vw = ws + V_OFF;
    bf16* wb = ws + WB_OFF;

    convert_w_kernel<<<40,  256, 0, stream>>>(Wq, Wk, Wv, wb);
    proj_all_kernel <<<512, 256, 0, stream>>>(x, y, wb, bq, bk, bv, qw, kw, vw);
    attn_kernel     <<<512, 256, 0, stream>>>(qw, kw, vw, out);
}